// Round 1
// 260.317 us; speedup vs baseline: 1.1206x; 1.1206x over previous
//
#include <hip/hip_runtime.h>
#include <cstddef>

#define NB 64
#define LL 512
#define HH 256
#define HD 128
#define NG 512
#define TI 16

typedef _Float16 half_t;
typedef _Float16 half8 __attribute__((ext_vector_type(8)));
typedef _Float16 half4 __attribute__((ext_vector_type(4)));
typedef float f32x4 __attribute__((ext_vector_type(4)));

#define MFMA16(a, b, c) __builtin_amdgcn_mfma_f32_16x16x32_f16((a), (b), (c), 0, 0, 0)

// LDS pitches (<=2-way bank aliasing, free on CDNA4)
#define FP 264   // sFeatb pitch (f16)
#define XP 522   // sXG pitch (f32): 4*XP%32 == 8 -> quads 8 banks apart
#define HBP 136  // sHb pitch (f16)

__device__ __forceinline__ float sigm(float x)  { return 1.0f / (1.0f + __expf(-x)); }
__device__ __forceinline__ float tanhf_(float x){ return 2.0f / (1.0f + __expf(-2.0f * x)) - 1.0f; }

// ---- prep: cast weights to f16, bsum = b_ih + b_hh ----
__global__ void prep_weights(const float* __restrict__ Wih, const float* __restrict__ Whh,
                             const float* __restrict__ bih, const float* __restrict__ bhh,
                             half_t* __restrict__ WihH, half_t* __restrict__ WhhH,
                             float* __restrict__ bsum)
{
    const int idx = blockIdx.x * 256 + threadIdx.x;
    if (idx < NG * HH) WihH[idx] = (half_t)Wih[idx];
    if (idx < NG * HD) WhhH[idx] = (half_t)Whh[idx];
    if (idx < NG)      bsum[idx] = bih[idx] + bhh[idx];
}

__global__ __launch_bounds__(512, 4) void span_lstm_mfma(
    const float* __restrict__ feats, const half_t* __restrict__ WihH,
    const half_t* __restrict__ WhhH, const float* __restrict__ bsum,
    const float* __restrict__ W_tri, const float* __restrict__ b_tri,
    const int* __restrict__ lens, float* __restrict__ out)
{
    // LDS: sXG 41760 (sFeatb 16896 aliased inside) + sHb 8704 + sEmitP 4096 = 54560 B
    //  -> 2 blocks/CU (109 KB of 160 KB); with <=128 VGPR that's 16 waves/CU.
    __shared__ __align__(16) float  sXG[20 * XP];
    __shared__ __align__(16) half_t sHb[2][16 * HBP];
    __shared__ __align__(16) float  sEmitP[4][2][TI][8];

    half_t* sFeatb = (half_t*)sXG;   // dead after A-frag hoist; sXG overwrites it

    const int tid = threadIdx.x;
    const int b  = blockIdx.x >> 5;
    const int i0 = (blockIdx.x & 31) * TI;
    const int lens_b = lens[b];

    const int lane = tid & 63, wv = tid >> 6;   // 8 waves
    const int lm = lane & 15;                   // m / n within 16-tile
    const int lq = lane >> 4;                   // quad
    const int jw = wv * 16;                     // this wave's hidden-column slice

    // ---- stage feats window (20 rows) as f16 ----
    for (int idx = tid; idx < 20 * 64; idx += 512) {
        const int p  = idx >> 6;
        const int k4 = (idx & 63) << 2;
        const int gp = i0 + p;
        float4 v = make_float4(0.f, 0.f, 0.f, 0.f);
        if (gp < LL) v = *(const float4*)(feats + ((size_t)b * LL + gp) * HH + k4);
        half4 hv = {(half_t)v.x, (half_t)v.y, (half_t)v.z, (half_t)v.w};
        *(half4*)(&sFeatb[p * FP + k4]) = hv;
    }
    __syncthreads();

    // ---- hoist A-frags (2 M-tiles x 8 K-frags) into registers ----
    half8 afr[2][8];
    #pragma unroll
    for (int mt = 0; mt < 2; ++mt)
        #pragma unroll
        for (int kf = 0; kf < 8; ++kf)
            afr[mt][kf] = *(const half8*)(&sFeatb[(16 * mt + lm) * FP + kf * 32 + lq * 8]);
    __syncthreads();   // all feats reads done before sXG overwrites the union

    // ---- phase 1: wave computes XG only for ITS gate columns (4 ta x 16 cols) ----
    // sXG becomes wave-private -> no barrier needed before the t-loop.
    #pragma unroll
    for (int ta = 0; ta < 4; ++ta) {
        const int gb = ta * HD + jw;
        const float bs = bsum[gb + lm];
        f32x4 acc0 = {0.f, 0.f, 0.f, 0.f}, acc1 = {0.f, 0.f, 0.f, 0.f};
        #pragma unroll
        for (int kf = 0; kf < 8; ++kf) {
            const half8 bfr = *(const half8*)(WihH + (size_t)(gb + lm) * HH + kf * 32 + lq * 8);
            acc0 = MFMA16(afr[0][kf], bfr, acc0);
            acc1 = MFMA16(afr[1][kf], bfr, acc1);
        }
        #pragma unroll
        for (int r = 0; r < 4; ++r)
            sXG[(lq * 4 + r) * XP + gb + lm] = acc0[r] + bs;
        if (lq == 0) {
            #pragma unroll
            for (int r = 0; r < 4; ++r)
                sXG[(16 + r) * XP + gb + lm] = acc1[r] + bs;
        }
    }

    // ---- Whh B-frags: 4 ta x 4 kf for this wave's 16 columns (64 VGPRs) ----
    half8 bf2[4][4];
    #pragma unroll
    for (int ta = 0; ta < 4; ++ta)
        #pragma unroll
        for (int kf = 0; kf < 4; ++kf)
            bf2[ta][kf] = *(const half8*)(WhhH + (size_t)(ta * HD + jw + lm) * HD
                                          + kf * 32 + lq * 8);

    const float wt0 = W_tri[jw + lm];
    const float wt1 = W_tri[HD + jw + lm];

    // zero-fill target for this block's output rows (replaces the 134 MB memset)
    f32x4* ob4 = (f32x4*)(out + ((size_t)b * LL + i0) * (LL * 2));
    const f32x4 zz = {0.f, 0.f, 0.f, 0.f};

    float cc4[4] = {0.f, 0.f, 0.f, 0.f};

    #pragma unroll
    for (int t = 0; t < 4; ++t) {
        float accg[4][4];
        if (t > 0) {
            half8 ah[4];
            #pragma unroll
            for (int kf = 0; kf < 4; ++kf)
                ah[kf] = *(const half8*)(&sHb[(t - 1) & 1][lm * HBP + kf * 32 + lq * 8]);
            #pragma unroll
            for (int ta = 0; ta < 4; ++ta) {
                f32x4 a = {0.f, 0.f, 0.f, 0.f};
                #pragma unroll
                for (int kf = 0; kf < 4; ++kf)
                    a = MFMA16(ah[kf], bf2[ta][kf], a);
                #pragma unroll
                for (int r = 0; r < 4; ++r) accg[ta][r] = a[r];
            }
        } else {
            #pragma unroll
            for (int ta = 0; ta < 4; ++ta)
                #pragma unroll
                for (int r = 0; r < 4; ++r) accg[ta][r] = 0.f;
        }
        // + XG (row s+t), wave-private columns
        #pragma unroll
        for (int ta = 0; ta < 4; ++ta)
            #pragma unroll
            for (int r = 0; r < 4; ++r)
                accg[ta][r] += sXG[(lq * 4 + r + t) * XP + ta * HD + jw + lm];

        // cell update (f32, in-lane)
        float hh[4];
        #pragma unroll
        for (int r = 0; r < 4; ++r) {
            const float ig = sigm(accg[0][r]);
            const float fg = sigm(accg[1][r]);
            const float gg = tanhf_(accg[2][r]);
            const float og = sigm(accg[3][r]);
            cc4[r] = fg * cc4[r] + ig * gg;
            hh[r]  = og * tanhf_(cc4[r]);
        }

        // publish new h (f16, double-buffered) — not needed after last step
        if (t < 3) {
            #pragma unroll
            for (int r = 0; r < 4; ++r)
                sHb[t & 1][(lq * 4 + r) * HBP + jw + lm] = (half_t)hh[r];
        }

        // ---- in-register emission partials: reduce over this wave's 16 j's ----
        #pragma unroll
        for (int r = 0; r < 4; ++r) {
            float e0 = hh[r] * wt0;
            float e1 = hh[r] * wt1;
            e0 += __shfl_xor(e0, 1);  e1 += __shfl_xor(e1, 1);
            e0 += __shfl_xor(e0, 2);  e1 += __shfl_xor(e1, 2);
            e0 += __shfl_xor(e0, 4);  e1 += __shfl_xor(e1, 4);
            e0 += __shfl_xor(e0, 8);  e1 += __shfl_xor(e1, 8);
            if (lm == 0) {
                sEmitP[t][0][lq * 4 + r][wv] = e0;
                sEmitP[t][1][lq * 4 + r][wv] = e1;
            }
        }

        // 16 KB of the output zero-fill per step (drains at this step's barrier)
        ob4[(t << 10) + tid]       = zz;
        ob4[(t << 10) + 512 + tid] = zz;

        __syncthreads();   // the ONE barrier per step: sHb + sEmitP visibility
    }

    // ---- finalize: one (t, tag, s) per thread; sum 8 wave partials, scatter spans ----
    if (tid < 128) {
        const int es = tid & 15, etag = (tid >> 4) & 1, t = tid >> 5;
        const float* pp = sEmitP[t][etag][es];
        float e = b_tri[etag];
        #pragma unroll
        for (int w8 = 0; w8 < 8; ++w8) e += pp[w8];

        const int i = i0 + es;
        const int rem = lens_b - i;
        const int sc = t + 1;
        if (rem > 0 && sc <= rem) {
            const int mm  = rem < 4 ? rem : 4;
            const int whi = (sc >= mm) ? 4 : sc;
            for (int w2 = sc; w2 <= whi; ++w2) {
                const int jj2 = i + w2 - 1;
                if (jj2 < LL)
                    out[(((size_t)b * LL + i) * LL + jj2) * 2 + etag] = e;
            }
        }
    }
}

extern "C" void kernel_launch(void* const* d_in, const int* in_sizes, int n_in,
                              void* d_out, int out_size, void* d_ws, size_t ws_size,
                              hipStream_t stream)
{
    const float* feats = (const float*)d_in[0];
    const float* W_ih  = (const float*)d_in[1];
    const float* W_hh  = (const float*)d_in[2];
    const float* b_ih  = (const float*)d_in[3];
    const float* b_hh  = (const float*)d_in[4];
    const float* W_tri = (const float*)d_in[5];
    const float* b_tri = (const float*)d_in[6];
    const int*   lens  = (const int*)d_in[7];
    float* out = (float*)d_out;

    // NOTE: no hipMemsetAsync — span_lstm_mfma zero-fills its own output slice.

    // ws layout: WihH (256 KB) | WhhH (128 KB) | bsum (2 KB)
    half_t* WihH = (half_t*)d_ws;
    half_t* WhhH = WihH + (size_t)NG * HH;
    float*  bsum = (float*)(WhhH + (size_t)NG * HD);

    prep_weights<<<(NG * HH + 255) / 256, 256, 0, stream>>>(W_ih, W_hh, b_ih, b_hh,
                                                            WihH, WhhH, bsum);
    span_lstm_mfma<<<NB * (LL / TI), 512, 0, stream>>>(feats, WihH, WhhH, bsum,
                                                       W_tri, b_tri, lens, out);
}